// Round 6
// baseline (62.202 us; speedup 1.0000x reference)
//
#include <hip/hip_runtime.h>

#define TSTEPS 256
#define NOBJ   8192
#define BATCH  64
#define DEMB   32
#define DATT   128

// ws layout (bytes)
#define EX_OFF     0
#define SEGOFF_OFF 163840
#define EMB_OFF    166400
#define WS_NEED    (EMB_OFF + 5 * NOBJ * DEMB * 4)

struct SP {
    const float* x[5]; const int* cls[5]; const int* seg[5];
    const float* W[5]; const float* bias[5];
    const float* x_ped; const float* x_ego; const float* h_ped;
    const float* Wp; const float* bp; const float* We; const float* be;
    const float* Wax; const float* Wah; const float* ba; const float* va;
    const float* W1; const float* b1; const float* W2; const float* b2;
    const float* W3; const float* b3;
    const int* t_ptr;
    float* out;
    float* ex;      // [5][8192]
    int* seg_off;   // [5][65]
    float* emb;     // [5][8192][32]
    int d[5];
    int use_emb;
};

__device__ __forceinline__ int load_t(const void* p) {
    unsigned w0 = *(const unsigned*)p;
    if (w0 < (unsigned)TSTEPS) return (int)w0;
    float f = __uint_as_float(w0);
    if (f >= 0.f && f < 256.f) return (int)f;
    return 8;
}

__device__ __forceinline__ float fast_tanh(float x) {
    float e = __expf(2.0f * x);
    return 1.0f - 2.0f / (e + 1.0f);
}

__device__ __forceinline__ int lower_bound(const int* a, int n, int v) {
    int lo = 0, hi = n;
    while (lo < hi) { int mid = (lo + hi) >> 1; if (a[mid] < v) lo = mid + 1; else hi = mid; }
    return lo;
}

// ---- kernel 1: scores (2 objects/thread, 8 lanes/object) + emb to ws.
// Self-contained: computes hW for the segments this block spans; block x==0
// of each type also writes seg_off for k_fin.
template<int D>
__device__ __forceinline__ void score_body(const SP& p, const int type, const int t,
                                           float* WaxT, float* W_s, float* b_s, float* hWl) {
    const int tid = threadIdx.x;
    const float* __restrict__ x   = p.x[type];
    const int*   __restrict__ cls = p.cls[type];
    const int*   __restrict__ seg = p.seg[type];

    if (blockIdx.x == 0 && tid <= BATCH)
        p.seg_off[type * 65 + tid] = lower_bound(seg, NOBJ, tid);

    const int o = tid >> 3;
    const int q = tid & 7;
    const int i0 = blockIdx.x * 64 + o;
    const int i1 = i0 + 32;

    // issue gathers early so latency overlaps LDS staging
    const int c0 = cls[i0 * TSTEPS + t];
    const int c1 = cls[i1 * TSTEPS + t];
    const int b0 = seg[i0];
    const int b1 = seg[i1];
    const int sfirst = seg[blockIdx.x * 64];
    const int slast  = seg[blockIdx.x * 64 + 63];
    float xv0[D], xv1[D];
    {
        const float* xr0 = x + (size_t)(i0 * TSTEPS + t) * D;
        const float* xr1 = x + (size_t)(i1 * TSTEPS + t) * D;
        #pragma unroll
        for (int k = 0; k < D; ++k) { xv0[k] = xr0[k]; xv1[k] = xr1[k]; }
    }

    for (int i = tid; i < DATT * DEMB; i += 256) {
        int k = i >> 7, j = i & 127;
        WaxT[j * DEMB + k] = p.Wax[i];
    }
    for (int i = tid; i < D * DEMB; i += 256) W_s[i] = p.W[type][i];
    if (tid < DEMB) b_s[tid] = p.bias[type][tid];

    // hW rows for the segments present in this block (typically 2)
    const int nseg = slast - sfirst + 1;
    for (int e2 = tid; e2 < nseg * DATT; e2 += 256) {
        const int s = sfirst + (e2 >> 7);
        const int j = e2 & 127;
        float a = p.ba[j];
        const float* h = p.h_ped + s * DEMB;
        #pragma unroll
        for (int k = 0; k < DEMB; ++k) a += h[k] * p.Wah[k * DATT + j];
        hWl[(s - sfirst) * DATT + j] = a;
    }
    __syncthreads();

    // emb for both objects, stored rotated by q (reg slot cc = logical chunk (cc+q)&7)
    float e0[DEMB], e1[DEMB];
    const float4* b4 = (const float4*)b_s;
    #pragma unroll
    for (int cc = 0; cc < 8; ++cc) {
        const int c = (cc + q) & 7;
        float4 a0 = b4[c], a1 = b4[c];
        #pragma unroll
        for (int k = 0; k < D; ++k) {
            const float4 w = *(const float4*)&W_s[k * DEMB + 4 * c];
            a0.x += xv0[k]*w.x; a0.y += xv0[k]*w.y; a0.z += xv0[k]*w.z; a0.w += xv0[k]*w.w;
            a1.x += xv1[k]*w.x; a1.y += xv1[k]*w.y; a1.z += xv1[k]*w.z; a1.w += xv1[k]*w.w;
        }
        e0[4*cc+0]=fmaxf(a0.x,0.f); e0[4*cc+1]=fmaxf(a0.y,0.f);
        e0[4*cc+2]=fmaxf(a0.z,0.f); e0[4*cc+3]=fmaxf(a0.w,0.f);
        e1[4*cc+0]=fmaxf(a1.x,0.f); e1[4*cc+1]=fmaxf(a1.y,0.f);
        e1[4*cc+2]=fmaxf(a1.z,0.f); e1[4*cc+3]=fmaxf(a1.w,0.f);
    }

    float sc0 = 0.f, sc1 = 0.f;
    const float4* hw0 = (const float4*)(hWl + (b0 - sfirst) * DATT + q * 16);
    const float4* hw1 = (const float4*)(hWl + (b1 - sfirst) * DATT + q * 16);
    const float4* va4 = (const float4*)(p.va + q * 16);
    #pragma unroll
    for (int w4 = 0; w4 < 4; ++w4) {
        const float4 h0 = hw0[w4], h1 = hw1[w4], vv = va4[w4];
        #pragma unroll
        for (int u = 0; u < 4; ++u) {
            const int j = q * 16 + w4 * 4 + u;
            const float* wrow = &WaxT[j * DEMB];
            float s0a=0.f, s0b=0.f, s1a=0.f, s1b=0.f;
            #pragma unroll
            for (int cc = 0; cc < 8; ++cc) {
                const int c = (cc + q) & 7;   // bank-group 4c disjoint across q, broadcast across o
                const float4 w = *(const float4*)&wrow[4 * c];
                s0a += e0[4*cc+0]*w.x + e0[4*cc+1]*w.y;
                s0b += e0[4*cc+2]*w.z + e0[4*cc+3]*w.w;
                s1a += e1[4*cc+0]*w.x + e1[4*cc+1]*w.y;
                s1b += e1[4*cc+2]*w.z + e1[4*cc+3]*w.w;
            }
            sc0 += fast_tanh((&h0.x)[u] + (s0a + s0b)) * (&vv.x)[u];
            sc1 += fast_tanh((&h1.x)[u] + (s1a + s1b)) * (&vv.x)[u];
        }
    }
    sc0 += __shfl_xor(sc0, 1); sc1 += __shfl_xor(sc1, 1);
    sc0 += __shfl_xor(sc0, 2); sc1 += __shfl_xor(sc1, 2);
    sc0 += __shfl_xor(sc0, 4); sc1 += __shfl_xor(sc1, 4);

    if (q == 0) {
        p.ex[type * NOBJ + i0] = (c0 != -1) ? __expf(sc0) : 0.f;
        p.ex[type * NOBJ + i1] = (c1 != -1) ? __expf(sc1) : 0.f;
    }
    if (p.use_emb) {
        // reg slot cc=0 holds logical chunk q; unconditional -> emb fully defined
        *(float4*)&p.emb[((size_t)type * NOBJ + i0) * DEMB + 4 * q] = make_float4(e0[0],e0[1],e0[2],e0[3]);
        *(float4*)&p.emb[((size_t)type * NOBJ + i1) * DEMB + 4 * q] = make_float4(e1[0],e1[1],e1[2],e1[3]);
    }
}

__global__ __launch_bounds__(256) void k_score(SP p) {
    __shared__ __align__(16) float WaxT[DATT * DEMB];   // 16 KB
    __shared__ __align__(16) float W_s[7 * DEMB];
    __shared__ __align__(16) float b_s[DEMB];
    __shared__ __align__(16) float hWl[BATCH * DATT];   // 32 KB (worst-case span)
    const int t = load_t(p.t_ptr);
    switch (blockIdx.y) {
        case 0: score_body<4>(p, 0, t, WaxT, W_s, b_s, hWl); break;
        case 1: score_body<6>(p, 1, t, WaxT, W_s, b_s, hWl); break;
        case 2: score_body<5>(p, 2, t, WaxT, W_s, b_s, hWl); break;
        case 3: score_body<7>(p, 3, t, WaxT, W_s, b_s, hWl); break;
        default: score_body<7>(p, 4, t, WaxT, W_s, b_s, hWl); break;
    }
}

// ---- kernel 2: one block per batch row. All 5 types' softmax+feature-sum,
// ped/ego embeddings, probs, feats, and the classifier head — no round-trips.
__global__ __launch_bounds__(256) void k_fin(SP p) {
    const int b   = blockIdx.x;
    const int tid = threadIdx.x;
    const int j   = tid & 31;
    const int sl  = tid >> 5;   // 0..7 object slot
    const int wv  = tid >> 6;   // 0..3 wave
    const int t   = load_t(p.t_ptr);

    __shared__ float feats_s[224];
    __shared__ float red4[4];
    __shared__ float ared[4][DEMB];
    __shared__ float h1s[DEMB], h2s[DEMB];

    // ped (cols 0..31) / ego (cols 192..223)
    if (tid < 64) {
        const bool ego = tid >= 32;
        const float* xr = (ego ? p.x_ego : p.x_ped) + (size_t)(b * TSTEPS + t) * 4;
        const float* W  = ego ? p.We : p.Wp;
        const float* bb = ego ? p.be : p.bp;
        float a = bb[j];
        #pragma unroll
        for (int k = 0; k < 4; ++k) a += xr[k] * W[k * DEMB + j];
        a = fmaxf(a, 0.f);
        const int col = ego ? 192 + j : j;
        feats_s[col] = a;
        p.out[64 + b * 224 + col] = a;
    }

    for (int type = 0; type < 5; ++type) {
        const float* __restrict__ ex = p.ex + type * NOBJ;
        const int lo = p.seg_off[type * 65 + b];
        const int hi = p.seg_off[type * 65 + b + 1];

        float s = 0.f;
        for (int i = lo + tid; i < hi; i += 256) s += ex[i];
        #pragma unroll
        for (int off = 32; off; off >>= 1) s += __shfl_xor(s, off);
        if ((tid & 63) == 0) red4[wv] = s;
        __syncthreads();
        const float inv = 1.0f / fmaxf(red4[0] + red4[1] + red4[2] + red4[3], 1e-30f);

        float acc = 0.f;
        float* pout = p.out + 64 + BATCH * 224 + type * NOBJ;
        if (p.use_emb) {
            const float* __restrict__ eb = p.emb + (size_t)type * NOBJ * DEMB;
            for (int i = lo + sl; i < hi; i += 8) {
                const float pr = ex[i] * inv;
                if (j == 0) pout[i] = pr;
                acc += pr * eb[(size_t)i * DEMB + j];   // 128B coalesced per slot
            }
        } else {
            const int d = p.d[type];
            float wj[7];
            for (int k = 0; k < d; ++k) wj[k] = p.W[type][k * DEMB + j];
            const float bj = p.bias[type][j];
            for (int i = lo + sl; i < hi; i += 8) {
                const float e = ex[i];
                const float pr = e * inv;
                if (j == 0) pout[i] = pr;
                if (e > 0.f) {
                    const float* xr = p.x[type] + (size_t)(i * TSTEPS + t) * d;
                    float a = bj;
                    for (int k = 0; k < d; ++k) a += xr[k] * wj[k];
                    acc += pr * fmaxf(a, 0.f);
                }
            }
        }
        acc += __shfl_xor(acc, 32);    // merge slot pairs within wave
        __syncthreads();
        if ((tid & 63) < 32) ared[wv][j] = acc;
        __syncthreads();
        if (tid < DEMB) {
            const float f = ared[0][tid] + ared[1][tid] + ared[2][tid] + ared[3][tid];
            feats_s[32 + type * 32 + tid] = f;
            p.out[64 + b * 224 + 32 * (1 + type) + tid] = f;
        }
    }
    __syncthreads();

    // head: h1 = relu(feats@W1+b1), 8 k-slices of 28 per channel
    float a1 = 0.f;
    {
        const int k0 = sl * 28;
        #pragma unroll 4
        for (int k = k0; k < k0 + 28; ++k)
            a1 += feats_s[k] * p.W1[k * DEMB + j];
    }
    a1 += __shfl_xor(a1, 32);
    __syncthreads();
    if ((tid & 63) < 32) ared[wv][j] = a1;
    __syncthreads();
    if (tid < DEMB)
        h1s[tid] = fmaxf(ared[0][tid] + ared[1][tid] + ared[2][tid] + ared[3][tid] + p.b1[tid], 0.f);
    __syncthreads();
    if (tid < DEMB) {
        float a2 = p.b2[tid];
        #pragma unroll
        for (int k = 0; k < DEMB; ++k) a2 += h1s[k] * p.W2[k * DEMB + tid];
        h2s[tid] = fmaxf(a2, 0.f);
    }
    __syncthreads();
    if (tid < DEMB) {
        float v = h2s[tid] * p.W3[tid];
        v += __shfl_xor(v, 16); v += __shfl_xor(v, 8);
        v += __shfl_xor(v, 4);  v += __shfl_xor(v, 2); v += __shfl_xor(v, 1);
        if (tid == 0) p.out[b] = v + p.b3[0];
    }
}

extern "C" void kernel_launch(void* const* d_in, const int* in_sizes, int n_in,
                              void* d_out, int out_size, void* d_ws, size_t ws_size,
                              hipStream_t stream) {
    (void)in_sizes; (void)n_in; (void)out_size;

    SP p;
    const int xi[5] = {3, 6, 9, 12, 15};
    const int wi[5] = {20, 22, 24, 26, 28};
    const int di[5] = {4, 6, 5, 7, 7};
    for (int tp = 0; tp < 5; ++tp) {
        p.x[tp]    = (const float*)d_in[xi[tp]];
        p.cls[tp]  = (const int*)d_in[xi[tp] + 1];
        p.seg[tp]  = (const int*)d_in[xi[tp] + 2];
        p.W[tp]    = (const float*)d_in[wi[tp]];
        p.bias[tp] = (const float*)d_in[wi[tp] + 1];
        p.d[tp]    = di[tp];
    }
    p.x_ped = (const float*)d_in[0];
    p.x_ego = (const float*)d_in[1];
    p.h_ped = (const float*)d_in[2];
    p.Wp = (const float*)d_in[18]; p.bp = (const float*)d_in[19];
    p.We = (const float*)d_in[30]; p.be = (const float*)d_in[31];
    p.Wax = (const float*)d_in[32]; p.Wah = (const float*)d_in[33];
    p.ba  = (const float*)d_in[34]; p.va  = (const float*)d_in[35];
    p.W1 = (const float*)d_in[36]; p.b1 = (const float*)d_in[37];
    p.W2 = (const float*)d_in[38]; p.b2 = (const float*)d_in[39];
    p.W3 = (const float*)d_in[40]; p.b3 = (const float*)d_in[41];
    p.t_ptr = (const int*)d_in[42];
    p.out = (float*)d_out;
    char* ws = (char*)d_ws;
    p.ex      = (float*)(ws + EX_OFF);
    p.seg_off = (int*)(ws + SEGOFF_OFF);
    p.emb     = (float*)(ws + EMB_OFF);
    p.use_emb = (ws_size >= (size_t)WS_NEED) ? 1 : 0;

    hipLaunchKernelGGL(k_score, dim3(NOBJ / 64, 5), dim3(256), 0, stream, p);
    hipLaunchKernelGGL(k_fin,   dim3(BATCH),        dim3(256), 0, stream, p);
}

// Round 7
// 50.996 us; speedup vs baseline: 1.2197x; 1.2197x over previous
//
#include <hip/hip_runtime.h>

#define TSTEPS 256
#define NOBJ   8192
#define BATCH  64
#define DEMB   32
#define DATT   128

// ws layout (bytes)
#define HW_OFF     0
#define EX_OFF     32768
#define SEGOFF_OFF 196608
#define EMB_OFF    199168
#define WS_NEED    (EMB_OFF + 5 * NOBJ * DEMB * 4)

struct SP {
    const float* x[5]; const int* cls[5]; const int* seg[5];
    const float* W[5]; const float* bias[5];
    const float* x_ped; const float* x_ego; const float* h_ped;
    const float* Wp; const float* bp; const float* We; const float* be;
    const float* Wax; const float* Wah; const float* ba; const float* va;
    const float* W1; const float* b1; const float* W2; const float* b2;
    const float* W3; const float* b3;
    const int* t_ptr;
    float* out;
    float* hW;      // [64][128]
    float* ex;      // [5][8192]
    int* seg_off;   // [5][65]
    float* emb;     // [5][8192][32]
    int d[5];
    int use_emb;
};

__device__ __forceinline__ int load_t(const void* p) {
    unsigned w0 = *(const unsigned*)p;
    if (w0 < (unsigned)TSTEPS) return (int)w0;
    float f = __uint_as_float(w0);
    if (f >= 0.f && f < 256.f) return (int)f;
    return 8;
}

__device__ __forceinline__ float fast_tanh(float x) {
    float e = __expf(2.0f * x);
    return 1.0f - 2.0f / (e + 1.0f);
}

__device__ __forceinline__ int lower_bound(const int* a, int n, int v) {
    int lo = 0, hi = n;
    while (lo < hi) { int mid = (lo + hi) >> 1; if (a[mid] < v) lo = mid + 1; else hi = mid; }
    return lo;
}

// ---- kernel 0: hW, ped/ego feats, seg offsets
__global__ __launch_bounds__(128) void k_prep(SP p) {
    const int b = blockIdx.x;
    const int j = threadIdx.x;
    const int t = load_t(p.t_ptr);
    float a = p.ba[j];
    const float* h = p.h_ped + b * DEMB;
    #pragma unroll
    for (int k = 0; k < DEMB; ++k) a += h[k] * p.Wah[k * DATT + j];
    p.hW[b * DATT + j] = a;

    if (j < DEMB) {
        const float* xp = p.x_ped + (size_t)(b * TSTEPS + t) * 4;
        float e = p.bp[j];
        #pragma unroll
        for (int k = 0; k < 4; ++k) e += xp[k] * p.Wp[k * DEMB + j];
        p.out[64 + b * 224 + j] = fmaxf(e, 0.f);
        const float* xe = p.x_ego + (size_t)(b * TSTEPS + t) * 4;
        float g = p.be[j];
        #pragma unroll
        for (int k = 0; k < 4; ++k) g += xe[k] * p.We[k * DEMB + j];
        p.out[64 + b * 224 + 192 + j] = fmaxf(g, 0.f);
    }
    if (j < 5) p.seg_off[j * 65 + b] = lower_bound(p.seg[j], NOBJ, b);
    if (b == 63 && j >= 5 && j < 10) p.seg_off[(j - 5) * 65 + 64] = NOBJ;
}

// ---- kernel 1: 16 lanes/object (j-slice of 8), 2 objects/thread, 32 obj/block.
template<int D>
__device__ __forceinline__ void score_body(const SP& p, const int type, const int t,
                                           float* WaxT, float* W_s, float* b_s) {
    const int tid = threadIdx.x;
    const float* __restrict__ x   = p.x[type];
    const int*   __restrict__ cls = p.cls[type];
    const int*   __restrict__ seg = p.seg[type];

    const int q = tid & 15;     // j-slice lane (16 per object)
    const int o = tid >> 4;     // object slot 0..15
    const int i0 = blockIdx.x * 32 + o;
    const int i1 = i0 + 16;

    // issue gathers early so latency overlaps LDS staging
    const int c0 = cls[i0 * TSTEPS + t];
    const int c1 = cls[i1 * TSTEPS + t];
    const int b0 = seg[i0];
    const int b1 = seg[i1];
    float xv0[D], xv1[D];
    {
        const float* xr0 = x + (size_t)(i0 * TSTEPS + t) * D;
        const float* xr1 = x + (size_t)(i1 * TSTEPS + t) * D;
        #pragma unroll
        for (int k = 0; k < D; ++k) { xv0[k] = xr0[k]; xv1[k] = xr1[k]; }
    }

    // stage Wax^T: LINEAR LDS writes (conflict-free); transposed gather on the
    // global side (16KB, L2-hot across 1280 blocks).  WaxT[j*32+k] = Wax[k][j].
    for (int i = tid; i < DATT * DEMB; i += 256) {
        const int j = i >> 5, k = i & 31;
        WaxT[i] = p.Wax[k * DATT + j];
    }
    for (int i = tid; i < D * DEMB; i += 256) W_s[i] = p.W[type][i];
    if (tid < DEMB) b_s[tid] = p.bias[type][tid];
    __syncthreads();

    // emb for both objects, stored rotated: reg slot cc holds logical chunk (cc+q)&7
    float e0[DEMB], e1[DEMB];
    const float4* b4 = (const float4*)b_s;
    #pragma unroll
    for (int cc = 0; cc < 8; ++cc) {
        const int c = (cc + q) & 7;
        float4 a0 = b4[c], a1 = b4[c];
        #pragma unroll
        for (int k = 0; k < D; ++k) {
            const float4 w = *(const float4*)&W_s[k * DEMB + 4 * c];
            a0.x += xv0[k]*w.x; a0.y += xv0[k]*w.y; a0.z += xv0[k]*w.z; a0.w += xv0[k]*w.w;
            a1.x += xv1[k]*w.x; a1.y += xv1[k]*w.y; a1.z += xv1[k]*w.z; a1.w += xv1[k]*w.w;
        }
        e0[4*cc+0]=fmaxf(a0.x,0.f); e0[4*cc+1]=fmaxf(a0.y,0.f);
        e0[4*cc+2]=fmaxf(a0.z,0.f); e0[4*cc+3]=fmaxf(a0.w,0.f);
        e1[4*cc+0]=fmaxf(a1.x,0.f); e1[4*cc+1]=fmaxf(a1.y,0.f);
        e1[4*cc+2]=fmaxf(a1.z,0.f); e1[4*cc+3]=fmaxf(a1.w,0.f);
    }

    // per-lane j-slice: j = q*8 + jo, jo = 0..7
    float hv0[8], hv1[8], vv[8];
    {
        const float* hp0 = p.hW + b0 * DATT + q * 8;
        const float* hp1 = p.hW + b1 * DATT + q * 8;
        const float* vp  = p.va + q * 8;
        *(float4*)(hv0)   = *(const float4*)(hp0);
        *(float4*)(hv0+4) = *(const float4*)(hp0+4);
        *(float4*)(hv1)   = *(const float4*)(hp1);
        *(float4*)(hv1+4) = *(const float4*)(hp1+4);
        *(float4*)(vv)    = *(const float4*)(vp);
        *(float4*)(vv+4)  = *(const float4*)(vp+4);
    }

    float sc0 = 0.f, sc1 = 0.f;
    #pragma unroll
    for (int jo = 0; jo < 8; ++jo) {
        const float* wrow = &WaxT[(q * 8 + jo) * DEMB];
        float s0a=0.f, s0b=0.f, s1a=0.f, s1b=0.f;
        #pragma unroll
        for (int cc = 0; cc < 8; ++cc) {
            const int c = (cc + q) & 7;   // bank-group 4c: 2-way across 16 q's (free); w reused for both objects
            const float4 w = *(const float4*)&wrow[4 * c];
            s0a += e0[4*cc+0]*w.x + e0[4*cc+1]*w.y;
            s0b += e0[4*cc+2]*w.z + e0[4*cc+3]*w.w;
            s1a += e1[4*cc+0]*w.x + e1[4*cc+1]*w.y;
            s1b += e1[4*cc+2]*w.z + e1[4*cc+3]*w.w;
        }
        sc0 += fast_tanh(hv0[jo] + (s0a + s0b)) * vv[jo];
        sc1 += fast_tanh(hv1[jo] + (s1a + s1b)) * vv[jo];
    }
    sc0 += __shfl_xor(sc0, 1); sc1 += __shfl_xor(sc1, 1);
    sc0 += __shfl_xor(sc0, 2); sc1 += __shfl_xor(sc1, 2);
    sc0 += __shfl_xor(sc0, 4); sc1 += __shfl_xor(sc1, 4);
    sc0 += __shfl_xor(sc0, 8); sc1 += __shfl_xor(sc1, 8);

    if (q == 0) {
        p.ex[type * NOBJ + i0] = (c0 != -1) ? __expf(sc0) : 0.f;
        p.ex[type * NOBJ + i1] = (c1 != -1) ? __expf(sc1) : 0.f;
    }
    if (p.use_emb && q < 8) {
        // reg slot cc=0 holds logical chunk q; lanes q=0..7 cover all 8 chunks
        *(float4*)&p.emb[((size_t)type * NOBJ + i0) * DEMB + 4 * q] = make_float4(e0[0],e0[1],e0[2],e0[3]);
        *(float4*)&p.emb[((size_t)type * NOBJ + i1) * DEMB + 4 * q] = make_float4(e1[0],e1[1],e1[2],e1[3]);
    }
}

__global__ __launch_bounds__(256, 4) void k_score(SP p) {
    __shared__ __align__(16) float WaxT[DATT * DEMB];   // 16 KB
    __shared__ __align__(16) float W_s[7 * DEMB];
    __shared__ __align__(16) float b_s[DEMB];
    const int t = load_t(p.t_ptr);
    switch (blockIdx.y) {
        case 0: score_body<4>(p, 0, t, WaxT, W_s, b_s); break;
        case 1: score_body<6>(p, 1, t, WaxT, W_s, b_s); break;
        case 2: score_body<5>(p, 2, t, WaxT, W_s, b_s); break;
        case 3: score_body<7>(p, 3, t, WaxT, W_s, b_s); break;
        default: score_body<7>(p, 4, t, WaxT, W_s, b_s); break;
    }
}

// ---- kernel 2: per (type,segment) block: denom + probs + feature sum
__global__ __launch_bounds__(256) void k_finish(SP p) {
    const int type = blockIdx.y;
    const int bseg = blockIdx.x;
    const int tid  = threadIdx.x;
    const int j    = tid & 31;
    const int sl   = tid >> 5;   // 0..7 object slot
    const int wv   = tid >> 6;
    const float* __restrict__ ex = p.ex + type * NOBJ;
    const int lo = p.seg_off[type * 65 + bseg];
    const int hi = p.seg_off[type * 65 + bseg + 1];

    __shared__ float red4[4];
    __shared__ float ared[4][DEMB];

    float s = 0.f;
    for (int i = lo + tid; i < hi; i += 256) s += ex[i];
    #pragma unroll
    for (int off = 32; off; off >>= 1) s += __shfl_xor(s, off);
    if ((tid & 63) == 0) red4[wv] = s;
    __syncthreads();
    const float inv = 1.0f / fmaxf(red4[0] + red4[1] + red4[2] + red4[3], 1e-30f);

    float acc = 0.f;
    float* pout = p.out + 64 + BATCH * 224 + type * NOBJ;
    if (p.use_emb) {
        const float* __restrict__ eb = p.emb + (size_t)type * NOBJ * DEMB;
        for (int i = lo + sl; i < hi; i += 8) {
            const float pr = ex[i] * inv;
            if (j == 0) pout[i] = pr;
            acc += pr * eb[(size_t)i * DEMB + j];   // 128B coalesced per slot
        }
    } else {
        const int t = load_t(p.t_ptr);
        const int d = p.d[type];
        float wj[7];
        for (int k = 0; k < d; ++k) wj[k] = p.W[type][k * DEMB + j];
        const float bj = p.bias[type][j];
        for (int i = lo + sl; i < hi; i += 8) {
            const float e = ex[i];
            const float pr = e * inv;
            if (j == 0) pout[i] = pr;
            if (e > 0.f) {
                const float* xr = p.x[type] + (size_t)(i * TSTEPS + t) * d;
                float a = bj;
                for (int k = 0; k < d; ++k) a += xr[k] * wj[k];
                acc += pr * fmaxf(a, 0.f);
            }
        }
    }
    acc += __shfl_xor(acc, 32);    // merge slot pairs within wave
    if ((tid & 63) < 32) ared[wv][j] = acc;
    __syncthreads();
    if (tid < DEMB) {
        const float f = ared[0][tid] + ared[1][tid] + ared[2][tid] + ared[3][tid];
        p.out[64 + bseg * 224 + 32 * (1 + type) + tid] = f;
    }
}

// ---- kernel 3: classifier head, one wave per batch row
__global__ __launch_bounds__(64) void k_head(SP p) {
    const int b   = blockIdx.x;
    const int tid = threadIdx.x;
    const int j    = tid & 31;
    const int half = tid >> 5;
    __shared__ float h1s[DEMB];
    __shared__ float h2s[DEMB];
    const float* feats = p.out + 64 + b * 224;

    float a = 0.f;
    const int k0 = half * 112;
    #pragma unroll 4
    for (int k = k0; k < k0 + 112; ++k)
        a += feats[k] * p.W1[k * DEMB + j];
    a += __shfl_xor(a, 32);
    if (half == 0) h1s[j] = fmaxf(a + p.b1[j], 0.f);
    __syncthreads();

    float a2 = 0.f;
    const int k2 = half * 16;
    #pragma unroll
    for (int k = k2; k < k2 + 16; ++k)
        a2 += h1s[k] * p.W2[k * DEMB + j];
    a2 += __shfl_xor(a2, 32);
    if (half == 0) h2s[j] = fmaxf(a2 + p.b2[j], 0.f);
    __syncthreads();

    if (half == 0) {
        float v = h2s[j] * p.W3[j];
        v += __shfl_xor(v, 16); v += __shfl_xor(v, 8);
        v += __shfl_xor(v, 4);  v += __shfl_xor(v, 2); v += __shfl_xor(v, 1);
        if (j == 0) p.out[b] = v + p.b3[0];
    }
}

extern "C" void kernel_launch(void* const* d_in, const int* in_sizes, int n_in,
                              void* d_out, int out_size, void* d_ws, size_t ws_size,
                              hipStream_t stream) {
    (void)in_sizes; (void)n_in; (void)out_size;

    SP p;
    const int xi[5] = {3, 6, 9, 12, 15};
    const int wi[5] = {20, 22, 24, 26, 28};
    const int di[5] = {4, 6, 5, 7, 7};
    for (int tp = 0; tp < 5; ++tp) {
        p.x[tp]    = (const float*)d_in[xi[tp]];
        p.cls[tp]  = (const int*)d_in[xi[tp] + 1];
        p.seg[tp]  = (const int*)d_in[xi[tp] + 2];
        p.W[tp]    = (const float*)d_in[wi[tp]];
        p.bias[tp] = (const float*)d_in[wi[tp] + 1];
        p.d[tp]    = di[tp];
    }
    p.x_ped = (const float*)d_in[0];
    p.x_ego = (const float*)d_in[1];
    p.h_ped = (const float*)d_in[2];
    p.Wp = (const float*)d_in[18]; p.bp = (const float*)d_in[19];
    p.We = (const float*)d_in[30]; p.be = (const float*)d_in[31];
    p.Wax = (const float*)d_in[32]; p.Wah = (const float*)d_in[33];
    p.ba  = (const float*)d_in[34]; p.va  = (const float*)d_in[35];
    p.W1 = (const float*)d_in[36]; p.b1 = (const float*)d_in[37];
    p.W2 = (const float*)d_in[38]; p.b2 = (const float*)d_in[39];
    p.W3 = (const float*)d_in[40]; p.b3 = (const float*)d_in[41];
    p.t_ptr = (const int*)d_in[42];
    p.out = (float*)d_out;
    char* ws = (char*)d_ws;
    p.hW      = (float*)(ws + HW_OFF);
    p.ex      = (float*)(ws + EX_OFF);
    p.seg_off = (int*)(ws + SEGOFF_OFF);
    p.emb     = (float*)(ws + EMB_OFF);
    p.use_emb = (ws_size >= (size_t)WS_NEED) ? 1 : 0;

    hipLaunchKernelGGL(k_prep,   dim3(BATCH),         dim3(DATT), 0, stream, p);
    hipLaunchKernelGGL(k_score,  dim3(NOBJ / 32, 5),  dim3(256),  0, stream, p);
    hipLaunchKernelGGL(k_finish, dim3(BATCH, 5),      dim3(256),  0, stream, p);
    hipLaunchKernelGGL(k_head,   dim3(BATCH),         dim3(64),   0, stream, p);
}

// Round 8
// 44.775 us; speedup vs baseline: 1.3892x; 1.1389x over previous
//
#include <hip/hip_runtime.h>

#define TSTEPS 256
#define NOBJ   8192
#define BATCH  64
#define DEMB   32
#define DATT   128

// ws layout (bytes)
#define HW_OFF     0
#define EX_OFF     32768
#define SEGOFF_OFF 196608
#define EMB_OFF    199168
#define WS_NEED    (EMB_OFF + 5 * NOBJ * DEMB * 4)

struct SP {
    const float* x[5]; const int* cls[5]; const int* seg[5];
    const float* W[5]; const float* bias[5];
    const float* x_ped; const float* x_ego; const float* h_ped;
    const float* Wp; const float* bp; const float* We; const float* be;
    const float* Wax; const float* Wah; const float* ba; const float* va;
    const float* W1; const float* b1; const float* W2; const float* b2;
    const float* W3; const float* b3;
    const int* t_ptr;
    float* out;
    float* hW;      // [64][128]
    float* ex;      // [5][8192]
    int* seg_off;   // [5][65]
    float* emb;     // [5][8192][32]
    int d[5];
    int use_emb;
};

__device__ __forceinline__ int load_t(const void* p) {
    unsigned w0 = *(const unsigned*)p;
    if (w0 < (unsigned)TSTEPS) return (int)w0;
    float f = __uint_as_float(w0);
    if (f >= 0.f && f < 256.f) return (int)f;
    return 8;
}

__device__ __forceinline__ float fast_tanh(float x) {
    float e = __expf(2.0f * x);
    return 1.0f - 2.0f / (e + 1.0f);
}

// ---- kernel 0: hW + ped/ego feats (blocks 0..63); seg_off scatter (blocks 64..383)
__global__ __launch_bounds__(128) void k_prep(SP p) {
    if (blockIdx.x >= BATCH) {
        // boundary scan: 320 blocks x 128 thr cover 5 types x 8192 objects
        const int g    = (blockIdx.x - BATCH) * 128 + threadIdx.x;
        const int type = g >> 13;            // 8192 per type
        const int i    = g & (NOBJ - 1);
        const int* __restrict__ seg = p.seg[type];
        const int sv = seg[i];
        const int pv = (i == 0) ? -1 : seg[i - 1];   // coalesced re-read
        // seg_off[type][v] = first index with seg >= v  (for v in (pv, sv])
        for (int v = pv + 1; v <= sv; ++v) p.seg_off[type * 65 + v] = i;
        if (i == NOBJ - 1)
            for (int v = sv + 1; v <= BATCH; ++v) p.seg_off[type * 65 + v] = NOBJ;
        return;
    }
    const int b = blockIdx.x;
    const int j = threadIdx.x;
    const int t = load_t(p.t_ptr);
    float a = p.ba[j];
    const float* h = p.h_ped + b * DEMB;
    #pragma unroll
    for (int k = 0; k < DEMB; ++k) a += h[k] * p.Wah[k * DATT + j];
    p.hW[b * DATT + j] = a;

    if (j < DEMB) {
        const float* xp = p.x_ped + (size_t)(b * TSTEPS + t) * 4;
        float e = p.bp[j];
        #pragma unroll
        for (int k = 0; k < 4; ++k) e += xp[k] * p.Wp[k * DEMB + j];
        p.out[64 + b * 224 + j] = fmaxf(e, 0.f);
        const float* xe = p.x_ego + (size_t)(b * TSTEPS + t) * 4;
        float g = p.be[j];
        #pragma unroll
        for (int k = 0; k < 4; ++k) g += xe[k] * p.We[k * DEMB + j];
        p.out[64 + b * 224 + 192 + j] = fmaxf(g, 0.f);
    }
}

// ---- kernel 1: 16 lanes/object, 2 objects/thread, 32 obj/block.
// Inverted loops: tanh-arg accumulators acc[8] live; emb computed chunk-by-chunk.
template<int D>
__device__ __forceinline__ void score_body(const SP& p, const int type, const int t,
                                           float* WaxT, float* W_s, float* b_s) {
    const int tid = threadIdx.x;
    const float* __restrict__ x   = p.x[type];
    const int*   __restrict__ cls = p.cls[type];
    const int*   __restrict__ seg = p.seg[type];

    const int q = tid & 15;     // j-slice lane (16 per object)
    const int o = tid >> 4;     // object slot 0..15
    const int i0 = blockIdx.x * 32 + o;
    const int i1 = i0 + 16;

    // issue all gathers early; latency overlaps LDS staging
    const int c0 = cls[i0 * TSTEPS + t];
    const int c1 = cls[i1 * TSTEPS + t];
    const int b0 = seg[i0];
    const int b1 = seg[i1];
    float xv0[D], xv1[D];
    {
        const float* xr0 = x + (size_t)(i0 * TSTEPS + t) * D;
        const float* xr1 = x + (size_t)(i1 * TSTEPS + t) * D;
        #pragma unroll
        for (int k = 0; k < D; ++k) { xv0[k] = xr0[k]; xv1[k] = xr1[k]; }
    }
    // per-lane j-slice operands (prefetch; consumed in epilogue)
    float hv0[8], hv1[8], vv[8];
    {
        const float* hp0 = p.hW + b0 * DATT + q * 8;
        const float* hp1 = p.hW + b1 * DATT + q * 8;
        const float* vp  = p.va + q * 8;
        *(float4*)(hv0)   = *(const float4*)(hp0);
        *(float4*)(hv0+4) = *(const float4*)(hp0+4);
        *(float4*)(hv1)   = *(const float4*)(hp1);
        *(float4*)(hv1+4) = *(const float4*)(hp1+4);
        *(float4*)(vv)    = *(const float4*)(vp);
        *(float4*)(vv+4)  = *(const float4*)(vp+4);
    }

    // stage Wax^T: linear LDS writes (conflict-free), transposed gather global-side
    for (int i = tid; i < DATT * DEMB; i += 256) {
        const int j = i >> 5, k = i & 31;
        WaxT[i] = p.Wax[k * DATT + j];
    }
    for (int i = tid; i < D * DEMB; i += 256) W_s[i] = p.W[type][i];
    if (tid < DEMB) b_s[tid] = p.bias[type][tid];
    __syncthreads();

    float acc0[8], acc1[8];
    #pragma unroll
    for (int jo = 0; jo < 8; ++jo) { acc0[jo] = 0.f; acc1[jo] = 0.f; }

    const float4* b4 = (const float4*)b_s;
    #pragma unroll
    for (int cc = 0; cc < 8; ++cc) {
        const int c = (cc + q) & 7;          // bank-group 4c: 2-way across lanes (free)
        // emb chunk c for both objects
        float4 a0 = b4[c], a1 = b4[c];
        #pragma unroll
        for (int k = 0; k < D; ++k) {
            const float4 w = *(const float4*)&W_s[k * DEMB + 4 * c];
            a0.x += xv0[k]*w.x; a0.y += xv0[k]*w.y; a0.z += xv0[k]*w.z; a0.w += xv0[k]*w.w;
            a1.x += xv1[k]*w.x; a1.y += xv1[k]*w.y; a1.z += xv1[k]*w.z; a1.w += xv1[k]*w.w;
        }
        a0.x = fmaxf(a0.x, 0.f); a0.y = fmaxf(a0.y, 0.f);
        a0.z = fmaxf(a0.z, 0.f); a0.w = fmaxf(a0.w, 0.f);
        a1.x = fmaxf(a1.x, 0.f); a1.y = fmaxf(a1.y, 0.f);
        a1.z = fmaxf(a1.z, 0.f); a1.w = fmaxf(a1.w, 0.f);

        if (p.use_emb && cc == 0 && q < 8) {   // chunk q: write once
            p.emb[((size_t)type * NOBJ + i0) * DEMB + 4 * q + 0] = a0.x;
            *(float4*)&p.emb[((size_t)type * NOBJ + i0) * DEMB + 4 * q] = a0;
            *(float4*)&p.emb[((size_t)type * NOBJ + i1) * DEMB + 4 * q] = a1;
        }
        #pragma unroll
        for (int jo = 0; jo < 8; ++jo) {
            const float4 w = *(const float4*)&WaxT[(q * 8 + jo) * DEMB + 4 * c];
            acc0[jo] += a0.x*w.x + a0.y*w.y + a0.z*w.z + a0.w*w.w;
            acc1[jo] += a1.x*w.x + a1.y*w.y + a1.z*w.z + a1.w*w.w;
        }
    }

    float sc0 = 0.f, sc1 = 0.f;
    #pragma unroll
    for (int jo = 0; jo < 8; ++jo) {
        sc0 += fast_tanh(hv0[jo] + acc0[jo]) * vv[jo];
        sc1 += fast_tanh(hv1[jo] + acc1[jo]) * vv[jo];
    }
    sc0 += __shfl_xor(sc0, 1); sc1 += __shfl_xor(sc1, 1);
    sc0 += __shfl_xor(sc0, 2); sc1 += __shfl_xor(sc1, 2);
    sc0 += __shfl_xor(sc0, 4); sc1 += __shfl_xor(sc1, 4);
    sc0 += __shfl_xor(sc0, 8); sc1 += __shfl_xor(sc1, 8);

    if (q == 0) {
        p.ex[type * NOBJ + i0] = (c0 != -1) ? __expf(sc0) : 0.f;
        p.ex[type * NOBJ + i1] = (c1 != -1) ? __expf(sc1) : 0.f;
    }
}

__global__ __launch_bounds__(256) void k_score(SP p) {
    __shared__ __align__(16) float WaxT[DATT * DEMB];   // 16 KB
    __shared__ __align__(16) float W_s[7 * DEMB];
    __shared__ __align__(16) float b_s[DEMB];
    const int t = load_t(p.t_ptr);
    switch (blockIdx.y) {
        case 0: score_body<4>(p, 0, t, WaxT, W_s, b_s); break;
        case 1: score_body<6>(p, 1, t, WaxT, W_s, b_s); break;
        case 2: score_body<5>(p, 2, t, WaxT, W_s, b_s); break;
        case 3: score_body<7>(p, 3, t, WaxT, W_s, b_s); break;
        default: score_body<7>(p, 4, t, WaxT, W_s, b_s); break;
    }
}

// ---- kernel 2: per (type,segment) block: denom + probs + feature sum
__global__ __launch_bounds__(256) void k_finish(SP p) {
    const int type = blockIdx.y;
    const int bseg = blockIdx.x;
    const int tid  = threadIdx.x;
    const int j    = tid & 31;
    const int sl   = tid >> 5;   // 0..7 object slot
    const int wv   = tid >> 6;
    const float* __restrict__ ex = p.ex + type * NOBJ;
    const int lo = p.seg_off[type * 65 + bseg];
    const int hi = p.seg_off[type * 65 + bseg + 1];

    __shared__ float red4[4];
    __shared__ float ared[4][DEMB];

    float s = 0.f;
    for (int i = lo + tid; i < hi; i += 256) s += ex[i];
    #pragma unroll
    for (int off = 32; off; off >>= 1) s += __shfl_xor(s, off);
    if ((tid & 63) == 0) red4[wv] = s;
    __syncthreads();
    const float inv = 1.0f / fmaxf(red4[0] + red4[1] + red4[2] + red4[3], 1e-30f);

    float acc = 0.f;
    float* pout = p.out + 64 + BATCH * 224 + type * NOBJ;
    if (p.use_emb) {
        const float* __restrict__ eb = p.emb + (size_t)type * NOBJ * DEMB;
        for (int i = lo + sl; i < hi; i += 8) {
            const float pr = ex[i] * inv;
            if (j == 0) pout[i] = pr;
            acc += pr * eb[(size_t)i * DEMB + j];   // 128B coalesced per slot
        }
    } else {
        const int t = load_t(p.t_ptr);
        const int d = p.d[type];
        float wj[7];
        for (int k = 0; k < d; ++k) wj[k] = p.W[type][k * DEMB + j];
        const float bj = p.bias[type][j];
        for (int i = lo + sl; i < hi; i += 8) {
            const float e = ex[i];
            const float pr = e * inv;
            if (j == 0) pout[i] = pr;
            if (e > 0.f) {
                const float* xr = p.x[type] + (size_t)(i * TSTEPS + t) * d;
                float a = bj;
                for (int k = 0; k < d; ++k) a += xr[k] * wj[k];
                acc += pr * fmaxf(a, 0.f);
            }
        }
    }
    acc += __shfl_xor(acc, 32);    // merge slot pairs within wave
    if ((tid & 63) < 32) ared[wv][j] = acc;
    __syncthreads();
    if (tid < DEMB) {
        const float f = ared[0][tid] + ared[1][tid] + ared[2][tid] + ared[3][tid];
        p.out[64 + bseg * 224 + 32 * (1 + type) + tid] = f;
    }
}

// ---- kernel 3: classifier head, one wave per batch row
__global__ __launch_bounds__(64) void k_head(SP p) {
    const int b   = blockIdx.x;
    const int tid = threadIdx.x;
    const int j    = tid & 31;
    const int half = tid >> 5;
    __shared__ float h1s[DEMB];
    __shared__ float h2s[DEMB];
    const float* feats = p.out + 64 + b * 224;

    float a = 0.f;
    const int k0 = half * 112;
    #pragma unroll 4
    for (int k = k0; k < k0 + 112; ++k)
        a += feats[k] * p.W1[k * DEMB + j];
    a += __shfl_xor(a, 32);
    if (half == 0) h1s[j] = fmaxf(a + p.b1[j], 0.f);
    __syncthreads();

    float a2 = 0.f;
    const int k2 = half * 16;
    #pragma unroll
    for (int k = k2; k < k2 + 16; ++k)
        a2 += h1s[k] * p.W2[k * DEMB + j];
    a2 += __shfl_xor(a2, 32);
    if (half == 0) h2s[j] = fmaxf(a2 + p.b2[j], 0.f);
    __syncthreads();

    if (half == 0) {
        float v = h2s[j] * p.W3[j];
        v += __shfl_xor(v, 16); v += __shfl_xor(v, 8);
        v += __shfl_xor(v, 4);  v += __shfl_xor(v, 2); v += __shfl_xor(v, 1);
        if (j == 0) p.out[b] = v + p.b3[0];
    }
}

extern "C" void kernel_launch(void* const* d_in, const int* in_sizes, int n_in,
                              void* d_out, int out_size, void* d_ws, size_t ws_size,
                              hipStream_t stream) {
    (void)in_sizes; (void)n_in; (void)out_size;

    SP p;
    const int xi[5] = {3, 6, 9, 12, 15};
    const int wi[5] = {20, 22, 24, 26, 28};
    const int di[5] = {4, 6, 5, 7, 7};
    for (int tp = 0; tp < 5; ++tp) {
        p.x[tp]    = (const float*)d_in[xi[tp]];
        p.cls[tp]  = (const int*)d_in[xi[tp] + 1];
        p.seg[tp]  = (const int*)d_in[xi[tp] + 2];
        p.W[tp]    = (const float*)d_in[wi[tp]];
        p.bias[tp] = (const float*)d_in[wi[tp] + 1];
        p.d[tp]    = di[tp];
    }
    p.x_ped = (const float*)d_in[0];
    p.x_ego = (const float*)d_in[1];
    p.h_ped = (const float*)d_in[2];
    p.Wp = (const float*)d_in[18]; p.bp = (const float*)d_in[19];
    p.We = (const float*)d_in[30]; p.be = (const float*)d_in[31];
    p.Wax = (const float*)d_in[32]; p.Wah = (const float*)d_in[33];
    p.ba  = (const float*)d_in[34]; p.va  = (const float*)d_in[35];
    p.W1 = (const float*)d_in[36]; p.b1 = (const float*)d_in[37];
    p.W2 = (const float*)d_in[38]; p.b2 = (const float*)d_in[39];
    p.W3 = (const float*)d_in[40]; p.b3 = (const float*)d_in[41];
    p.t_ptr = (const int*)d_in[42];
    p.out = (float*)d_out;
    char* ws = (char*)d_ws;
    p.hW      = (float*)(ws + HW_OFF);
    p.ex      = (float*)(ws + EX_OFF);
    p.seg_off = (int*)(ws + SEGOFF_OFF);
    p.emb     = (float*)(ws + EMB_OFF);
    p.use_emb = (ws_size >= (size_t)WS_NEED) ? 1 : 0;

    hipLaunchKernelGGL(k_prep,   dim3(BATCH + 5 * NOBJ / 128), dim3(128), 0, stream, p);
    hipLaunchKernelGGL(k_score,  dim3(NOBJ / 32, 5),           dim3(256), 0, stream, p);
    hipLaunchKernelGGL(k_finish, dim3(BATCH, 5),               dim3(256), 0, stream, p);
    hipLaunchKernelGGL(k_head,   dim3(BATCH),                  dim3(64),  0, stream, p);
}